// Round 3
// baseline (3094.721 us; speedup 1.0000x reference)
//
#include <hip/hip_runtime.h>

// ---------------------------------------------------------------- constants
#define EPSV 1e-5f
constexpr int Bsz = 4, T0 = 512, Dm = 512, TT = 513, NHh = 8, KK = 4;
constexpr int IN = 1024, DHd = 128, NCc = 1000;
constexpr int ROWS = Bsz * TT; // 2052
constexpr int NCH = 9;         // chunks of 64: 8*64 + 1 = 513

__device__ __forceinline__ float siluf(float x) { return x / (1.f + __expf(-x)); }

// ---------------------------------------------------------------- concat x + cls
__global__ __launch_bounds__(256) void concat_kernel(const float* __restrict__ x,
                                                     const float* __restrict__ cls,
                                                     float* __restrict__ h) {
    int idx = blockIdx.x * 256 + threadIdx.x;
    if (idx >= Bsz * TT * Dm) return;
    int d = idx & (Dm - 1);
    int bt = idx >> 9;
    int t = bt % TT, b = bt / TT;
    h[idx] = (t < T0) ? x[((size_t)(b * T0 + t)) * Dm + d] : cls[d];
}

// ---------------------------------------------------------------- LayerNorm rows of D=512
__global__ __launch_bounds__(256) void ln_kernel(const float* __restrict__ in,
                                                 const float* __restrict__ s,
                                                 const float* __restrict__ bb,
                                                 float* __restrict__ out) {
    int row = blockIdx.x, tid = threadIdx.x;
    const float* r = in + (size_t)row * Dm;
    __shared__ float s1[4], s2[4];
    float x0 = r[tid], x1 = r[tid + 256];
    float sum = x0 + x1, sq = x0 * x0 + x1 * x1;
#pragma unroll
    for (int o = 32; o > 0; o >>= 1) { sum += __shfl_xor(sum, o); sq += __shfl_xor(sq, o); }
    if ((tid & 63) == 0) { s1[tid >> 6] = sum; s2[tid >> 6] = sq; }
    __syncthreads();
    sum = s1[0] + s1[1] + s1[2] + s1[3];
    sq  = s2[0] + s2[1] + s2[2] + s2[3];
    float mu = sum / Dm, var = sq / Dm - mu * mu, inv = rsqrtf(var + EPSV);
    out[(size_t)row * Dm + tid]       = (x0 - mu) * inv * s[tid] + bb[tid];
    out[(size_t)row * Dm + tid + 256] = (x1 - mu) * inv * s[tid + 256] + bb[tid + 256];
}

// ---------------------------------------------------------------- generic f32 GEMM
__global__ __launch_bounds__(256) void gemm_kernel(const float* __restrict__ A, int lda,
                                                   const float* __restrict__ W, int ldw,
                                                   const float* __restrict__ bias,
                                                   const float* __restrict__ resid, int ldr,
                                                   float* __restrict__ Cout, int ldc,
                                                   int M, int Kd, float scale) {
    __shared__ __align__(16) float As[16][68];
    __shared__ __align__(16) float Bs[16][64];
    int tid = threadIdx.x;
    int tx = tid & 15, ty = tid >> 4;
    int m0 = blockIdx.y * 64, n0 = blockIdx.x * 64;
    int arow = tid >> 2, akp = (tid & 3) * 4;
    int brow = tid >> 4, bnp = (tid & 15) * 4;
    float acc[4][4] = {};
    for (int k0 = 0; k0 < Kd; k0 += 16) {
        float4 av = make_float4(0.f, 0.f, 0.f, 0.f);
        int gm = m0 + arow;
        if (gm < M) av = *(const float4*)(A + (size_t)gm * lda + k0 + akp);
        As[akp + 0][arow] = av.x; As[akp + 1][arow] = av.y;
        As[akp + 2][arow] = av.z; As[akp + 3][arow] = av.w;
        float4 wv = *(const float4*)(W + (size_t)(k0 + brow) * ldw + n0 + bnp);
        Bs[brow][bnp + 0] = wv.x; Bs[brow][bnp + 1] = wv.y;
        Bs[brow][bnp + 2] = wv.z; Bs[brow][bnp + 3] = wv.w;
        __syncthreads();
#pragma unroll
        for (int k = 0; k < 16; k++) {
            float4 a  = *(const float4*)&As[k][ty * 4];
            float4 bv = *(const float4*)&Bs[k][tx * 4];
            float aa[4] = {a.x, a.y, a.z, a.w};
            float bb2[4] = {bv.x, bv.y, bv.z, bv.w};
#pragma unroll
            for (int i = 0; i < 4; i++)
#pragma unroll
                for (int j = 0; j < 4; j++) acc[i][j] += aa[i] * bb2[j];
        }
        __syncthreads();
    }
#pragma unroll
    for (int i = 0; i < 4; i++) {
        int gm = m0 + ty * 4 + i;
        if (gm >= M) continue;
        float* crow = Cout + (size_t)gm * ldc + n0 + tx * 4;
        const float* rrow = resid ? (resid + (size_t)gm * ldr + n0 + tx * 4) : nullptr;
#pragma unroll
        for (int j = 0; j < 4; j++) {
            float vsum = acc[i][j] * scale;
            if (bias) vsum += bias[n0 + tx * 4 + j];
            if (rrow) vsum += rrow[j];
            crow[j] = vsum;
        }
    }
}

// ---------------------------------------------------------------- causal depthwise conv (K=4) + SiLU
__global__ __launch_bounds__(256) void conv_silu_kernel(const float* __restrict__ up,
                                                        const float* __restrict__ ck,
                                                        const float* __restrict__ cb,
                                                        float* __restrict__ xc) {
    int idx = blockIdx.x * 256 + threadIdx.x;
    if (idx >= ROWS * IN) return;
    int c = idx & (IN - 1);
    int bt = idx >> 10;
    int t = bt % TT, b = bt / TT;
    float acc = cb[c];
#pragma unroll
    for (int j = 0; j < KK; j++) {
        int tt = t - (KK - 1) + j;
        if (tt >= 0) acc += up[((size_t)(b * TT + tt)) * (2 * IN) + c] * ck[c * KK + j];
    }
    xc[idx] = siluf(acc);
}

// ---------------------------------------------------------------- input/forget gate projections
__global__ __launch_bounds__(256) void gates_kernel(const float* __restrict__ xc,
                                                    const float* __restrict__ wig, const float* __restrict__ big,
                                                    const float* __restrict__ wfg, const float* __restrict__ bfg,
                                                    float* __restrict__ ip, float* __restrict__ fp) {
    int row = blockIdx.x, tid = threadIdx.x;
    __shared__ float sx[IN];
    for (int i = tid; i < IN; i += 256) sx[i] = xc[(size_t)row * IN + i];
    __syncthreads();
    int g = tid >> 4, l = tid & 15;
    const float* w = (g < 8) ? wig : wfg;
    int h = g & 7;
    float acc = 0.f;
    for (int kk = l; kk < IN; kk += 16) acc += sx[kk] * w[kk * NHh + h];
#pragma unroll
    for (int o = 8; o > 0; o >>= 1) acc += __shfl_down(acc, o, 16);
    if (l == 0) {
        if (g < 8) ip[(size_t)row * NHh + h] = acc + big[h];
        else       fp[(size_t)row * NHh + h] = acc + bfg[h];
    }
}

// ---------------------------------------------------------------- chunkwise mLSTM
// Kernel A: sequential scalar gate scan per chain (32 chains).
// G_t = ip_t - F_t (F = cumsum logsigmoid(fp)), M_t = running max(0, G).
// Chunk-boundary Mb_c and decay exp(Mb_{c-1}-Mb_c).
__global__ __launch_bounds__(64) void gate_scan_kernel(const float* __restrict__ ip,
        const float* __restrict__ fp, float* __restrict__ gG, float* __restrict__ gM,
        float* __restrict__ gMb, float* __restrict__ gDec) {
    int chain = threadIdx.x;
    if (chain >= Bsz * NHh) return;
    int b = chain >> 3, h = chain & 7;
    float F = 0.f, M = 0.f, Mbprev = 0.f;
    for (int t = 0; t < TT; t++) {
        size_t gi = (size_t)(b * TT + t) * NHh + h;
        float fpv = fp[gi], ipv = ip[gi];
        float fl = (fpv >= 0.f) ? -log1pf(__expf(-fpv)) : (fpv - log1pf(__expf(fpv)));
        F += fl;
        float G = ipv - F;
        M = fmaxf(M, G);
        gG[chain * TT + t] = G;
        gM[chain * TT + t] = M;
        if (((t & 63) == 63) || t == TT - 1) {
            int c = t >> 6;
            gMb[chain * NCH + c] = M;
            gDec[chain * NCH + c] = __expf(Mbprev - M);
            Mbprev = M;
        }
    }
}

// Kernel B1: per-chunk local state P[d][e] = sum_j exp(G_j - Mb_c) k_j[d] v_j[e]
// and nP[d] = sum_j w_j k_j[d].  grid (NCH, 32)
__global__ __launch_bounds__(256) void chunk_state_kernel(const float* __restrict__ kk,
        const float* __restrict__ vv, const float* __restrict__ gG,
        const float* __restrict__ gMb, float* __restrict__ P, float* __restrict__ nP) {
    int c = blockIdx.x, chain = blockIdx.y;
    int b = chain >> 3, h = chain & 7;
    int t0 = c * 64;
    int nvalid = min(64, TT - t0);
    __shared__ float sK[32][128], sV[32][128], sw[64];
    int tid = threadIdx.x;
    if (tid < 64) {
        float Mb = gMb[chain * NCH + c];
        sw[tid] = (tid < nvalid) ? __expf(gG[chain * TT + t0 + tid] - Mb) : 0.f;
    }
    int e = tid & 127, dg = (tid >> 7) * 64;
    float4 acc[16];
#pragma unroll
    for (int i = 0; i < 16; i++) acc[i] = make_float4(0.f, 0.f, 0.f, 0.f);
    float na = 0.f;
    for (int jh = 0; jh < 2; jh++) {
        // stage 32 rows of K,V
        int lrow = tid >> 5, lcol = (tid & 31) * 4;
        for (int rr = 0; rr < 4; rr++) {
            int r = lrow + rr * 8;
            int gr = jh * 32 + r;
            float4 kv = make_float4(0.f,0.f,0.f,0.f), vvv = kv;
            if (gr < nvalid) {
                size_t gb = ((size_t)(b * TT + t0 + gr)) * IN + h * DHd + lcol;
                kv = *(const float4*)(kk + gb);
                vvv = *(const float4*)(vv + gb);
            }
            *(float4*)&sK[r][lcol] = kv;
            *(float4*)&sV[r][lcol] = vvv;
        }
        __syncthreads();
        int jmax = min(32, nvalid - jh * 32);
        for (int j = 0; j < jmax; j++) {
            float wvj = sw[jh * 32 + j] * sV[j][e];
            const float4* kr = (const float4*)&sK[j][dg];
#pragma unroll
            for (int d4 = 0; d4 < 16; d4++) {
                float4 kq = kr[d4];
                acc[d4].x += kq.x * wvj; acc[d4].y += kq.y * wvj;
                acc[d4].z += kq.z * wvj; acc[d4].w += kq.w * wvj;
            }
        }
        if (tid < 128) {
            for (int j = 0; j < jmax; j++) na += sw[jh * 32 + j] * sK[j][tid];
        }
        __syncthreads();
    }
    float* Pbase = P + (((size_t)(c * 32 + chain)) << 14);
#pragma unroll
    for (int d4 = 0; d4 < 16; d4++) {
        Pbase[(size_t)(dg + d4 * 4 + 0) * 128 + e] = acc[d4].x;
        Pbase[(size_t)(dg + d4 * 4 + 1) * 128 + e] = acc[d4].y;
        Pbase[(size_t)(dg + d4 * 4 + 2) * 128 + e] = acc[d4].z;
        Pbase[(size_t)(dg + d4 * 4 + 3) * 128 + e] = acc[d4].w;
    }
    if (tid < 128) nP[(size_t)(c * 32 + chain) * 128 + tid] = na;
}

// Kernel B2: in-place exclusive combine over chunks: P[c] <- state BEFORE chunk c.
__global__ __launch_bounds__(256) void chunk_combine_kernel(float* __restrict__ P,
        const float* __restrict__ gDec) {
    int chain = blockIdx.x >> 6;
    int idx = (blockIdx.x & 63) * 256 + threadIdx.x;
    float run = 0.f;
    for (int c = 0; c < NCH; c++) {
        size_t a = (((size_t)(c * 32 + chain)) << 14) + idx;
        float tmp = P[a];
        P[a] = run;
        run = run * gDec[chain * NCH + c] + tmp;
    }
}

__global__ __launch_bounds__(256) void n_combine_kernel(float* __restrict__ nP,
        const float* __restrict__ gDec) {
    int gidx = blockIdx.x * 256 + threadIdx.x;
    int chain = gidx >> 7, d = gidx & 127;
    float run = 0.f;
    for (int c = 0; c < NCH; c++) {
        size_t a = (size_t)(c * 32 + chain) * 128 + d;
        float tmp = nP[a];
        nP[a] = run;
        run = run * gDec[chain * NCH + c] + tmp;
    }
}

// Kernel C: per-chunk outputs. grid (NCH, 32), 256 threads.
// h_t = [ sum_{j<=t,chunk} D[t][j] v_j + exp(Mb_{c-1}-M_t) * (CB q_t) ] / max(|den|,1)
// D[t][j] = (q_t . k_j) exp(G_j - M_t);  den = sum_j D[t][j] + exp(Mb_{c-1}-M_t)(q_t . nb)
__global__ __launch_bounds__(256) void chunk_out_kernel(const float* __restrict__ qq,
        const float* __restrict__ kk, const float* __restrict__ vv,
        const float* __restrict__ gG, const float* __restrict__ gM,
        const float* __restrict__ gMb, const float* __restrict__ P,
        const float* __restrict__ nP, float* __restrict__ hs) {
    int c = blockIdx.x, chain = blockIdx.y;
    int b = chain >> 3, h = chain & 7;
    int t0 = c * 64;
    int nvalid = min(64, TT - t0);
    __shared__ float smem[13248];
    float* sG  = smem;          // 64
    float* sM  = smem + 64;     // 64
    float* sWr = smem + 128;    // 64
    float* sInv= smem + 192;    // 64
    float* sNb = smem + 256;    // 128
    float (*sD)[65] = (float(*)[65])(smem + 384);          // 64x65
    float* scr = smem + 384 + 64 * 65;                     // 8704 floats scratch
    int tid = threadIdx.x;

    float Mbprev = (c > 0) ? gMb[chain * NCH + c - 1] : 0.f;
    if (tid < 64) {
        bool val = tid < nvalid;
        sG[tid] = val ? gG[chain * TT + t0 + tid] : -1e30f;
        float Mv = val ? gM[chain * TT + t0 + tid] : 1e30f;
        sM[tid] = Mv;
        sWr[tid] = val ? __expf(Mbprev - Mv) : 0.f;
    }
    if (tid >= 128 && tid < 256) sNb[tid - 128] = nP[(size_t)(c * 32 + chain) * 128 + (tid - 128)];
    __syncthreads();

    // ---- Phase 1: S = Q K^T over two 64-dim halves; acc in regs
    float (*Qh)[68] = (float(*)[68])scr;           // 64x68
    float (*Kh)[68] = (float(*)[68])(scr + 64 * 68);
    int j = tid & 63, ig = (tid >> 6) * 16;
    float accS[16];
#pragma unroll
    for (int i = 0; i < 16; i++) accS[i] = 0.f;
    float qnb = 0.f;
    for (int dh = 0; dh < 2; dh++) {
        int lr = tid >> 2, c0 = (tid & 3) * 16;
        bool val = lr < nvalid;
        size_t gb = ((size_t)(b * TT + t0 + lr)) * IN + h * DHd + dh * 64 + c0;
#pragma unroll
        for (int i = 0; i < 4; i++) {
            float4 qv = val ? *(const float4*)(qq + gb + i * 4) : make_float4(0.f,0.f,0.f,0.f);
            float4 kv = val ? *(const float4*)(kk + gb + i * 4) : make_float4(0.f,0.f,0.f,0.f);
            *(float4*)&Qh[lr][c0 + i * 4] = qv;
            *(float4*)&Kh[lr][c0 + i * 4] = kv;
        }
        __syncthreads();
#pragma unroll
        for (int d4 = 0; d4 < 16; d4++) {
            float4 kf = *(const float4*)&Kh[j][d4 * 4];
#pragma unroll
            for (int i = 0; i < 16; i++) {
                float4 qf = *(const float4*)&Qh[ig + i][d4 * 4];
                accS[i] += qf.x * kf.x + qf.y * kf.y + qf.z * kf.z + qf.w * kf.w;
            }
        }
        if (tid < 64) {
            for (int d = 0; d < 64; d++) qnb += Qh[tid][d] * sNb[dh * 64 + d];
        }
        __syncthreads();
    }
    // weights -> sD
    {
        float Gj = sG[j];
#pragma unroll
        for (int i = 0; i < 16; i++) {
            int irow = ig + i;
            float w = (j <= irow) ? __expf(Gj - sM[irow]) : 0.f;
            sD[irow][j] = accS[i] * w;
        }
    }
    __syncthreads();
    // ---- Phase 2: denominators
    if (tid < 64) {
        float s = 0.f;
        for (int jj = 0; jj < 64; jj++) s += sD[tid][jj];
        float den = s + sWr[tid] * qnb;
        sInv[tid] = 1.f / fmaxf(fabsf(den), 1.f);
    }
    __syncthreads();
    // ---- Phase 3a: intra H = D @ V
    float (*sV)[128] = (float(*)[128])scr;         // 64x128
    {
        int lrow = tid >> 5, lcol = (tid & 31) * 4;
        for (int rr = 0; rr < 8; rr++) {
            int r = lrow + rr * 8;
            float4 vvv = make_float4(0.f,0.f,0.f,0.f);
            if (r < nvalid) {
                size_t gb = ((size_t)(b * TT + t0 + r)) * IN + h * DHd + lcol;
                vvv = *(const float4*)(vv + gb);
            }
            *(float4*)&sV[r][lcol] = vvv;
        }
    }
    __syncthreads();
    int e = tid & 127, rg = (tid >> 7) * 32;
    float accD[32], accI[32];
#pragma unroll
    for (int r = 0; r < 32; r++) { accD[r] = 0.f; accI[r] = 0.f; }
    for (int jj = 0; jj < nvalid; jj++) {
        float vvv = sV[jj][e];
#pragma unroll 8
        for (int r = 0; r < 32; r++) accD[r] += sD[rg + r][jj] * vvv;
    }
    __syncthreads();   // done with sD and sV; regions reused below
    // ---- Phase 3b: inter H += wr * (CB q): CB layout [d][e]
    float (*sCB)[128] = (float(*)[128])(smem + 384);        // 64x128 (overlaps sD)
    float (*Qh2)[68]  = (float(*)[68])(smem + 384 + 64*128); // 64x68
    const float* CBbase = P + (((size_t)(c * 32 + chain)) << 14);
    for (int dh = 0; dh < 2; dh++) {
        {
            int dr = tid >> 5, dc = (tid & 31) * 4;
            for (int rr = 0; rr < 8; rr++) {
                int d = dr + rr * 8;
                *(float4*)&sCB[d][dc] = *(const float4*)(CBbase + (size_t)(dh * 64 + d) * 128 + dc);
            }
            int lr = tid >> 2, c0 = (tid & 3) * 16;
            bool val = lr < nvalid;
            size_t gb = ((size_t)(b * TT + t0 + lr)) * IN + h * DHd + dh * 64 + c0;
#pragma unroll
            for (int i = 0; i < 4; i++) {
                float4 qv = val ? *(const float4*)(qq + gb + i * 4) : make_float4(0.f,0.f,0.f,0.f);
                *(float4*)&Qh2[lr][c0 + i * 4] = qv;
            }
        }
        __syncthreads();
        for (int dd = 0; dd < 64; dd++) {
            float cbv = sCB[dd][e];
#pragma unroll 8
            for (int r = 0; r < 32; r++) accI[r] += Qh2[rg + r][dd] * cbv;
        }
        __syncthreads();
    }
    // ---- store
    for (int r = 0; r < 32; r++) {
        int irow = rg + r;
        if (irow < nvalid)
            hs[((size_t)(b * TT + t0 + irow)) * IN + h * DHd + e] =
                (accD[r] + sWr[irow] * accI[r]) * sInv[irow];
    }
}

// ---------------------------------------------------------------- per-head norm * hn_s * silu(z)
__global__ __launch_bounds__(64) void headnorm_kernel(const float* __restrict__ hs,
                                                      const float* __restrict__ hn,
                                                      const float* __restrict__ up,
                                                      float* __restrict__ out) {
    int idx = blockIdx.x;
    int h = idx & 7, bt = idx >> 3;
    int tid = threadIdx.x;
    size_t base = (size_t)bt * IN + h * DHd;
    float x0 = hs[base + tid], x1 = hs[base + 64 + tid];
    float sum = x0 + x1, sq = x0 * x0 + x1 * x1;
#pragma unroll
    for (int o = 32; o > 0; o >>= 1) { sum += __shfl_xor(sum, o); sq += __shfl_xor(sq, o); }
    float mu = sum / DHd, var = sq / DHd - mu * mu, inv = rsqrtf(var + EPSV);
    size_t zb = (size_t)bt * (2 * IN) + IN + h * DHd;
    out[base + tid]      = (x0 - mu) * inv * hn[h * DHd + tid]      * siluf(up[zb + tid]);
    out[base + 64 + tid] = (x1 - mu) * inv * hn[h * DHd + 64 + tid] * siluf(up[zb + 64 + tid]);
}

// ---------------------------------------------------------------- final classifier head
__global__ __launch_bounds__(256) void classifier_kernel(const float* __restrict__ hbuf,
                                                         const float* __restrict__ s, const float* __restrict__ bb,
                                                         const float* __restrict__ fw, const float* __restrict__ fb,
                                                         float* __restrict__ out) {
    int b = blockIdx.x, tid = threadIdx.x;
    const float* r = hbuf + ((size_t)b * TT + TT - 1) * Dm;
    __shared__ float vbuf[Dm];
    __shared__ float s1[4], s2[4];
    float x0 = r[tid], x1 = r[tid + 256];
    float sum = x0 + x1, sq = x0 * x0 + x1 * x1;
#pragma unroll
    for (int o = 32; o > 0; o >>= 1) { sum += __shfl_xor(sum, o); sq += __shfl_xor(sq, o); }
    if ((tid & 63) == 0) { s1[tid >> 6] = sum; s2[tid >> 6] = sq; }
    __syncthreads();
    sum = s1[0] + s1[1] + s1[2] + s1[3];
    sq  = s2[0] + s2[1] + s2[2] + s2[3];
    float mu = sum / Dm, var = sq / Dm - mu * mu, inv = rsqrtf(var + EPSV);
    float n0 = (x0 - mu) * inv * s[tid] + bb[tid];
    float n1 = (x1 - mu) * inv * s[tid + 256] + bb[tid + 256];
    vbuf[tid] = fmaxf(n0, 0.f);
    vbuf[tid + 256] = fmaxf(n1, 0.f);
    __syncthreads();
    for (int j = tid; j < NCc; j += 256) {
        float acc = fb[j];
        for (int kk = 0; kk < Dm; kk++) acc += vbuf[kk] * fw[kk * NCc + j];
        out[b * NCc + j] = acc;
    }
}

// ---------------------------------------------------------------- launch
extern "C" void kernel_launch(void* const* d_in, const int* in_sizes, int n_in,
                              void* d_out, int out_size, void* d_ws, size_t ws_size,
                              hipStream_t stream) {
    const float* x      = (const float*)d_in[0];
    const float* cls    = (const float*)d_in[1];
    const float* ln_s   = (const float*)d_in[2];
    const float* ln_b   = (const float*)d_in[3];
    const float* w_up   = (const float*)d_in[4];
    const float* b_up   = (const float*)d_in[5];
    const float* conv_k = (const float*)d_in[6];
    const float* conv_b = (const float*)d_in[7];
    const float* w_q    = (const float*)d_in[8];
    const float* w_k    = (const float*)d_in[9];
    const float* w_v    = (const float*)d_in[10];
    const float* w_ig   = (const float*)d_in[11];
    const float* b_ig   = (const float*)d_in[12];
    const float* w_fg   = (const float*)d_in[13];
    const float* b_fg   = (const float*)d_in[14];
    const float* hn_s   = (const float*)d_in[15];
    const float* w_down = (const float*)d_in[16];
    const float* b_down = (const float*)d_in[17];
    const float* fcls   = (const float*)d_in[18];
    const float* fclb   = (const float*)d_in[19];
    const float* fc_w   = (const float*)d_in[20];
    const float* fc_b   = (const float*)d_in[21];
    float* out = (float*)d_out;

    float* ws = (float*)d_ws;
    size_t off = 0;
    float* f_h  = ws + off; off += (size_t)ROWS * Dm;
    float* f_xn = ws + off; off += (size_t)ROWS * Dm;
    float* f_up = ws + off; off += (size_t)ROWS * 2 * IN;
    float* f_xc = ws + off; off += (size_t)ROWS * IN;
    float* f_q  = ws + off; off += (size_t)ROWS * IN;
    float* f_k  = ws + off; off += (size_t)ROWS * IN;
    float* f_v  = ws + off; off += (size_t)ROWS * IN;
    float* f_hs = ws + off; off += (size_t)ROWS * IN;
    float* f_ip = ws + off; off += (size_t)ROWS * NHh;
    float* f_fp = ws + off; off += (size_t)ROWS * NHh;
    float* g_G  = ws + off; off += 32 * TT;
    float* g_M  = ws + off; off += 32 * TT;
    float* g_Mb = ws + off; off += 32 * NCH;
    float* g_De = ws + off; off += 32 * NCH;
    float* g_P  = ws + off; off += (size_t)NCH * 32 * DHd * DHd;  // 4.7M
    float* g_nP = ws + off; off += (size_t)NCH * 32 * DHd;

    const float kscale = 0.08838834764831845f; // DH^-0.5

    concat_kernel<<<(ROWS * Dm + 255) / 256, 256, 0, stream>>>(x, cls, f_h);

    for (int blk = 0; blk < 2; blk++) {
        const float* p_ln_s = ln_s + blk * Dm;
        const float* p_ln_b = ln_b + blk * Dm;
        const float* p_wup  = w_up + (size_t)blk * Dm * 2 * IN;
        const float* p_bup  = b_up + (size_t)blk * 2 * IN;
        const float* p_ck   = conv_k + (size_t)blk * IN * KK;
        const float* p_cb   = conv_b + (size_t)blk * IN;
        const float* p_wq   = w_q + (size_t)blk * IN * IN;
        const float* p_wk   = w_k + (size_t)blk * IN * IN;
        const float* p_wv   = w_v + (size_t)blk * IN * IN;
        const float* p_wig  = w_ig + (size_t)blk * IN * NHh;
        const float* p_big  = b_ig + (size_t)blk * NHh;
        const float* p_wfg  = w_fg + (size_t)blk * IN * NHh;
        const float* p_bfg  = b_fg + (size_t)blk * NHh;
        const float* p_hns  = hn_s + (size_t)blk * NHh * DHd;
        const float* p_wd   = w_down + (size_t)blk * IN * Dm;
        const float* p_bd   = b_down + (size_t)blk * Dm;

        ln_kernel<<<ROWS, 256, 0, stream>>>(f_h, p_ln_s, p_ln_b, f_xn);

        gemm_kernel<<<dim3(2 * IN / 64, (ROWS + 63) / 64), 256, 0, stream>>>(
            f_xn, Dm, p_wup, 2 * IN, p_bup, nullptr, 0, f_up, 2 * IN, ROWS, Dm, 1.f);

        conv_silu_kernel<<<(ROWS * IN + 255) / 256, 256, 0, stream>>>(f_up, p_ck, p_cb, f_xc);

        gemm_kernel<<<dim3(IN / 64, (ROWS + 63) / 64), 256, 0, stream>>>(
            f_xc, IN, p_wq, IN, nullptr, nullptr, 0, f_q, IN, ROWS, IN, 1.f);
        gemm_kernel<<<dim3(IN / 64, (ROWS + 63) / 64), 256, 0, stream>>>(
            f_xc, IN, p_wk, IN, nullptr, nullptr, 0, f_k, IN, ROWS, IN, kscale);
        gemm_kernel<<<dim3(IN / 64, (ROWS + 63) / 64), 256, 0, stream>>>(
            f_up, 2 * IN, p_wv, IN, nullptr, nullptr, 0, f_v, IN, ROWS, IN, 1.f);

        gates_kernel<<<ROWS, 256, 0, stream>>>(f_xc, p_wig, p_big, p_wfg, p_bfg, f_ip, f_fp);

        // chunkwise-parallel mLSTM
        gate_scan_kernel<<<1, 64, 0, stream>>>(f_ip, f_fp, g_G, g_M, g_Mb, g_De);
        chunk_state_kernel<<<dim3(NCH, 32), 256, 0, stream>>>(f_k, f_v, g_G, g_Mb, g_P, g_nP);
        chunk_combine_kernel<<<32 * 64, 256, 0, stream>>>(g_P, g_De);
        n_combine_kernel<<<16, 256, 0, stream>>>(g_nP, g_De);
        chunk_out_kernel<<<dim3(NCH, 32), 256, 0, stream>>>(f_q, f_k, f_v, g_G, g_M, g_Mb,
                                                            g_P, g_nP, f_hs);

        headnorm_kernel<<<ROWS * NHh, 64, 0, stream>>>(f_hs, p_hns, f_up, f_xc);

        gemm_kernel<<<dim3(Dm / 64, (ROWS + 63) / 64), 256, 0, stream>>>(
            f_xc, IN, p_wd, Dm, p_bd, f_h, Dm, f_h, Dm, ROWS, IN, 1.f);
    }

    classifier_kernel<<<Bsz, 256, 0, stream>>>(f_h, fcls, fclb, fc_w, fc_b, out);
}